// Round 22
// baseline (106.695 us; speedup 1.0000x reference)
//
#include <hip/hip_runtime.h>

#define NB 32      // batch
#define NC 256     // planes
#define NO 128     // inplanes (output channels)
#define HH 28
#define HW 784     // 28*28
#define OH 56

typedef unsigned short u16;
typedef __attribute__((ext_vector_type(8))) short bf16x8;
typedef __attribute__((ext_vector_type(4))) float f32x4;
typedef __attribute__((ext_vector_type(8))) unsigned short u16x8;

#define MFMA(A,B,C) __builtin_amdgcn_mfma_f32_16x16x32_bf16(A,B,C,0,0,0)

__device__ __forceinline__ u16 f2bf(float f) {
    unsigned u = __float_as_uint(f);
    unsigned r = (u + 0x7fffu + ((u >> 16) & 1u)) >> 16;
    return (u16)r;
}

// ---------------------------------------------------------------------------
// k_prep: grid-concat of prep_x ([0,1024)) and misc ([1024,2192)).
// (frozen from r21)
// ---------------------------------------------------------------------------
__global__ __launch_bounds__(256) void k_prep(
    const float* __restrict__ x, const float* __restrict__ pb1a,
    u16* __restrict__ xT2, float* __restrict__ rng,
    const float* __restrict__ w2, const float* __restrict__ w1,
    const float* __restrict__ wup,
    u16* __restrict__ wT2, u16* __restrict__ wc2T,
    u16* __restrict__ wupT, uint4* __restrict__ r1T4)
{
    __shared__ float sx[8][HW];        // 25088 B (prep_x blocks only)
    __shared__ float smx[8][4], smn[8][4];

    if (blockIdx.x >= 1024) {
        int blk = blockIdx.x - 1024;
        if (blk < 288) {
            int g = blk * 256 + threadIdx.x;          // 9*32*256
            int o = g & 255;
            int cb = (g >> 8) & 31;
            int tap = g >> 13;
            int u = 2 - tap / 3, v = 2 - tap % 3;
            u16x8 out;
#pragma unroll
            for (int ci = 0; ci < 8; ++ci) {
                int c = cb * 8 + ci;
                out[ci] = f2bf(w2[((c * NC + o) * 3 + u) * 3 + v]);
            }
            *(u16x8*)(wT2 + (size_t)g * 8) = out;
        } else if (blk < 432) {
            const int taps[9] = {0, 2, 6, 8, 1, 7, 3, 5, 4};
            int g = (blk - 288) * 256 + threadIdx.x;  // 9*32*128
            int o = g & 127;
            int cb = (g >> 7) & 31;
            int s = g >> 12;
            int tap = taps[s];
            u16x8 out;
#pragma unroll
            for (int ci = 0; ci < 8; ++ci) {
                int c = cb * 8 + ci;
                out[ci] = f2bf(w1[(c * NO + o) * 9 + tap]);
            }
            *(u16x8*)(wc2T + (size_t)g * 8) = out;
        } else if (blk < 464) {
            int g = (blk - 432) * 256 + threadIdx.x;  // 4*16*128
            int o = g & 127;
            int kb = (g >> 7) & 15;
            int p = g >> 11;
            u16x8 out;
#pragma unroll
            for (int ki = 0; ki < 8; ++ki) {
                int k = kb * 8 + ki;
                out[ki] = f2bf(wup[(k * NO + o) * 4 + p]);
            }
            *(u16x8*)(wupT + (size_t)g * 8) = out;
        } else {
            int g = (blk - 464) * 256 + threadIdx.x;  // 180224
            int i = g % 176;
            int bc = g / 176;                  // b*32 + cb
            int b = bc >> 5, cb = bc & 31;
            int row, cx;
            if (i < 32)      { row = 0;  cx = i; }
            else if (i < 64) { row = 29; cx = i - 32; }
            else {
                int j = i - 64;
                row = 1 + (j >> 2);
                int k = j & 3;
                cx = (k == 0) ? 0 : 28 + k;    // 0,29,30,31
            }
            r1T4[((b * 30 + row) * 32 + cb) * 32 + cx] = make_uint4(0, 0, 0, 0);
        }
        return;
    }

    // ---- prep_x (float4 loads)
    int t = threadIdx.x;
    int b = blockIdx.x >> 5, cb = blockIdx.x & 31;
    float b1a = pb1a[0];
    const float* xb = x + ((size_t)b * NC + cb * 8) * HW;

    float mx[8], mn[8];
#pragma unroll
    for (int ci = 0; ci < 8; ++ci) { mx[ci] = -1e30f; mn[ci] = 1e30f; }
#pragma unroll
    for (int ci = 0; ci < 8; ++ci) {
        const float4* xb4 = (const float4*)(xb + ci * HW);
        float4* sx4 = (float4*)sx[ci];
        if (t < 196) {
            float4 v = xb4[t];
            sx4[t] = v;
            mx[ci] = fmaxf(fmaxf(v.x, v.y), fmaxf(v.z, v.w));
            mn[ci] = fminf(fminf(v.x, v.y), fminf(v.z, v.w));
        }
    }
    int lane = t & 63, wv = t >> 6;
#pragma unroll
    for (int ci = 0; ci < 8; ++ci) {
        float a = mx[ci], i = mn[ci];
        for (int off = 32; off; off >>= 1) {
            a = fmaxf(a, __shfl_down(a, off, 64));
            i = fminf(i, __shfl_down(i, off, 64));
        }
        if (lane == 0) { smx[ci][wv] = a; smn[ci][wv] = i; }
    }
    __syncthreads();
    if (t < 8) {
        float a = fmaxf(fmaxf(smx[t][0], smx[t][1]), fmaxf(smx[t][2], smx[t][3]));
        float i = fminf(fminf(smn[t][0], smn[t][1]), fminf(smn[t][2], smn[t][3]));
        rng[b * NC + cb * 8 + t] = a - i;
    }
    for (int g = t; g < 960; g += 256) {
        int ry = g >> 5, cx = g & 31;
        int y = ry - 1, xx = cx - 1;
        bool valid = (y >= 0 && y < HH && xx >= 0 && xx < HH);
        u16x8 out;
#pragma unroll
        for (int ci = 0; ci < 8; ++ci) {
            float f = valid ? sx[ci][y * 28 + xx] + b1a : 0.f;
            out[ci] = f2bf(f);
        }
        *(u16x8*)(xT2 + ((((size_t)b * 30 + ry) * 32 + cb) * 32 + cx) * 8) = out;
    }
}

// ---------------------------------------------------------------------------
// k_conv1x: grid-concat of conv1 (blocks [0,448)) and pack_xup ([448,1344)).
// (frozen from r21 — best measured)
// ---------------------------------------------------------------------------
__global__ __launch_bounds__(512, 4) void k_conv1x(
    const u16* __restrict__ xT2, const u16* __restrict__ wT2,
    const float* __restrict__ pb1b, const float* __restrict__ pb2a,
    u16* __restrict__ r1T,
    const float* __restrict__ x, const float* __restrict__ rng,
    const float* __restrict__ pb1a, u16* __restrict__ xupT)
{
    __shared__ u16 sA[6 * 16 * 32 * 8];   // 49152 B (conv1); reused by pack_xup
    if (blockIdx.x >= 448) {
        // ---- pack_xup with local select: block = one (b, qy)
        int blk = blockIdx.x - 448;        // 896 = 32b * 28qy
        int tid = threadIdx.x;
        int b = blk / 28;
        int qy = blk - b * 28;
        float b1a = pb1a[0];

        float* srng = (float*)sA;          // 256 floats
        int* ssel = (int*)(sA + 2048);     // 128 ints

        if (tid < 256) srng[tid] = rng[b * NC + tid];
        __syncthreads();
        if (tid < 256) {
            float v = srng[tid];
            int rank = 0;
            for (int j = 0; j < NC; ++j) {
                float u = srng[j];
                rank += (u < v) || (u == v && j < tid);
            }
            if (rank >= NC / 2) ssel[rank - NC / 2] = tid;
        }
        __syncthreads();

        int cx = tid & 31;
        int kb = tid >> 5;
        bool valid = cx < 28;
        const float* xb = x + (size_t)b * NC * HW + qy * 28 + (valid ? cx : 0);
        u16x8 out;
#pragma unroll
        for (int ki = 0; ki < 8; ++ki) {
            int ch = ssel[kb * 8 + ki];
            float f = valid ? xb[ch * HW] + b1a : 0.f;
            out[ki] = f2bf(f);
        }
        size_t g = ((size_t)(b * 28 + qy) * 16 + kb) * 32 + cx;
        *(u16x8*)(xupT + g * 8) = out;
        return;
    }

    // ---- conv1 (frozen r19/r21 structure)
    int tid = threadIdx.x;
    int wave = tid >> 6, lane = tid & 63;
    int wpi = wave >> 2;
    int wo = wave & 3;
    int l15 = lane & 15, lg = lane >> 4;

    int idx = blockIdx.x;             // 448
    int b = idx / 14;
    int rem = idx - b * 14;
    int rg = rem >> 1;
    int og = rem & 1;
    int y0 = rg * 4;

    float b1b = pb1b[0], b2a = pb2a[0];

    int bOff[2];
#pragma unroll
    for (int ot = 0; ot < 2; ++ot)
        bOff[ot] = (lg * 256 + (og * 128 + wo * 32 + ot * 16 + l15)) * 16;

    f32x4 acc[4][2] = {};
    const char* wq = (const char*)wT2;
    const char* ap0 = (const char*)sA;
    const uint4* gx = (const uint4*)xT2;
    uint4* dst = (uint4*)sA;

    int aLane = (2 * wpi) * 8192 + lg * 512 + l15 * 16;

    for (int half = 0; half < 2; ++half) {
        if (half) __syncthreads();
#pragma unroll
        for (int i = 0; i < 6; ++i)
            dst[tid + i * 512] = gx[(b * 30 + y0 + i) * 1024 + half * 512 + tid];
        __syncthreads();

        for (int cc = 0; cc < 128; cc += 32) {
            int c0 = half * 128 + cc;
            int aBase = aLane + cc * 64;
#pragma unroll
            for (int dx = 0; dx < 3; ++dx) {
                bf16x8 w[3][2];
#pragma unroll
                for (int dy = 0; dy < 3; ++dy)
#pragma unroll
                    for (int ot = 0; ot < 2; ++ot)
                        w[dy][ot] = *(const bf16x8*)(wq +
                            (bOff[ot] + (dy * 3 + dx) * 131072 + c0 * 512));
                bf16x8 a[4][2];
#pragma unroll
                for (int r = 0; r < 4; ++r)
#pragma unroll
                    for (int h = 0; h < 2; ++h)
                        a[r][h] = *(const bf16x8*)(ap0 +
                            (aBase + r * 8192 + (h * 16 + dx) * 16));
#pragma unroll
                for (int dy = 0; dy < 3; ++dy)
#pragma unroll
                    for (int m = 0; m < 2; ++m)
#pragma unroll
                        for (int h = 0; h < 2; ++h)
#pragma unroll
                            for (int ot = 0; ot < 2; ++ot)
                                acc[m * 2 + h][ot] =
                                    MFMA(a[m + dy][h], w[dy][ot], acc[m * 2 + h][ot]);
            }
        }
    }

#pragma unroll
    for (int m = 0; m < 2; ++m)
#pragma unroll
        for (int h = 0; h < 2; ++h) {
            int y = y0 + 2 * wpi + m;
            int x0 = h * 16 + lg * 4;
            if (x0 >= 28) continue;
#pragma unroll
            for (int ot = 0; ot < 2; ++ot) {
                int o = og * 128 + wo * 32 + ot * 16 + l15;
                size_t base = ((((size_t)b * 30 + y + 1) * 32 + (o >> 3)) * 32 + (x0 + 1)) * 8 + (o & 7);
#pragma unroll
                for (int r = 0; r < 4; ++r) {
                    float f = fmaxf(acc[m * 2 + h][ot][r] + b1b, 0.f) + b2a;
                    r1T[base + (size_t)r * 8] = f2bf(f);
                }
            }
        }
}

// ---------------------------------------------------------------------------
// conv2 + upsample via MFMA, qy-split for occupancy:
//  grid 448 = 32b x 14 rg2 (2 output rows each); slab = 3 padded rows = 48KB
//  (+20% staging vs 4-row, no o-split). 8 waves = 2 wpi(row) x 4 wo(32 o).
//  acc[4 par][2 pt][2 ot] = 64 VGPR; w streamed per-parity (<=8 live).
//  launch_bounds(512,3): 3 waves/SIMD, no idle CUs.
// ---------------------------------------------------------------------------
__global__ __launch_bounds__(512, 3) void k_conv2_mfma(
    const u16* __restrict__ r1T, const u16* __restrict__ xupT,
    const u16* __restrict__ wc2T, const u16* __restrict__ wupT,
    const float* __restrict__ pscale, const float* __restrict__ pb2b,
    float* __restrict__ out)
{
    __shared__ uint4 sA2[3072];       // 49152 B: padded rows y0..y0+2
    int tid = threadIdx.x;
    int wave = tid >> 6, lane = tid & 63;
    int wpi = wave >> 2;              // row 0..1
    int wo = wave & 3;                // o-group of 32
    int l15 = lane & 15, lg = lane >> 4;

    int idx = blockIdx.x;             // 448 = 32b * 14
    int b = idx / 14;
    int rg2 = idx - b * 14;
    int y0 = rg2 * 2;

    float scale = pscale[0], b2b = pb2b[0];

    // stage 3-row r1T slab (contiguous 48KB)
    {
        const uint4* src = (const uint4*)(r1T + (size_t)(b * 30 + y0) * 8192);
#pragma unroll
        for (int i = 0; i < 6; ++i)
            sA2[tid + i * 512] = src[tid + i * 512];
    }
    __syncthreads();

    f32x4 acc[4][2][2] = {};          // [parity][pt(qx half)][ot]

    const char* sp = (const char*)sA2;
    const char* wp = (const char*)wc2T;

    int aBase[2];
#pragma unroll
    for (int pt = 0; pt < 2; ++pt)
        aBase[pt] = (((wpi + 1) * 32 + lg) * 32 + (pt * 16 + l15 + 1)) * 16;
    int bBase = (lg * 128 + wo * 32 + l15) * 16;

    for (int c0 = 0; c0 < 256; c0 += 32) {
        // A fragments once per c0: [pt][variant 0=D,1=C,2=B,3=A]
        bf16x8 a[2][4];
#pragma unroll
        for (int pt = 0; pt < 2; ++pt) {
            const char* ap = sp + (aBase[pt] + c0 * 64);
            a[pt][0] = *(const bf16x8*)(ap);
            a[pt][1] = *(const bf16x8*)(ap - 16);
            a[pt][2] = *(const bf16x8*)(ap - 16384);
            a[pt][3] = *(const bf16x8*)(ap - 16400);
        }
        // parity 0: slots 0..3 with variants D,C,B,A
        {
            bf16x8 w[4][2];
#pragma unroll
            for (int s = 0; s < 4; ++s)
#pragma unroll
                for (int ot = 0; ot < 2; ++ot)
                    w[s][ot] = *(const bf16x8*)(wp + (bBase + s * 65536 + c0 * 256 + ot * 256));
#pragma unroll
            for (int pt = 0; pt < 2; ++pt)
#pragma unroll
                for (int s = 0; s < 4; ++s)
#pragma unroll
                    for (int ot = 0; ot < 2; ++ot)
                        acc[0][pt][ot] = MFMA(a[pt][s], w[s][ot], acc[0][pt][ot]);
        }
        // parity 1: slots 4,5 with variants D,B
        {
            bf16x8 w[2][2];
#pragma unroll
            for (int s = 0; s < 2; ++s)
#pragma unroll
                for (int ot = 0; ot < 2; ++ot)
                    w[s][ot] = *(const bf16x8*)(wp + (bBase + (4 + s) * 65536 + c0 * 256 + ot * 256));
#pragma unroll
            for (int pt = 0; pt < 2; ++pt)
#pragma unroll
                for (int ot = 0; ot < 2; ++ot) {
                    acc[1][pt][ot] = MFMA(a[pt][0], w[0][ot], acc[1][pt][ot]);
                    acc[1][pt][ot] = MFMA(a[pt][2], w[1][ot], acc[1][pt][ot]);
                }
        }
        // parity 2: slots 6,7 with variants D,C
        {
            bf16x8 w[2][2];
#pragma unroll
            for (int s = 0; s < 2; ++s)
#pragma unroll
                for (int ot = 0; ot < 2; ++ot)
                    w[s][ot] = *(const bf16x8*)(wp + (bBase + (6 + s) * 65536 + c0 * 256 + ot * 256));
#pragma unroll
            for (int pt = 0; pt < 2; ++pt)
#pragma unroll
                for (int ot = 0; ot < 2; ++ot) {
                    acc[2][pt][ot] = MFMA(a[pt][0], w[0][ot], acc[2][pt][ot]);
                    acc[2][pt][ot] = MFMA(a[pt][1], w[1][ot], acc[2][pt][ot]);
                }
        }
        // parity 3: slot 8 with variant D
        {
            bf16x8 w[2];
#pragma unroll
            for (int ot = 0; ot < 2; ++ot)
                w[ot] = *(const bf16x8*)(wp + (bBase + 8 * 65536 + c0 * 256 + ot * 256));
#pragma unroll
            for (int pt = 0; pt < 2; ++pt)
#pragma unroll
                for (int ot = 0; ot < 2; ++ot)
                    acc[3][pt][ot] = MFMA(a[pt][0], w[ot], acc[3][pt][ot]);
        }
    }

    // mid-transform: pad-zero / scale+b2b
    int qy = y0 + wpi;
#pragma unroll
    for (int pt = 0; pt < 2; ++pt) {
        int qx0 = pt * 16 + lg * 4;
        bool zr = (qy == 0);
#pragma unroll
        for (int ot = 0; ot < 2; ++ot)
#pragma unroll
            for (int r = 0; r < 4; ++r) {
                bool zc = (qx0 + r == 0);
                float a0 = acc[0][pt][ot][r], a1 = acc[1][pt][ot][r];
                float a2 = acc[2][pt][ot][r], a3 = acc[3][pt][ot][r];
                acc[0][pt][ot][r] = (zr || zc) ? 0.f : fmaf(a0, scale, b2b);
                acc[1][pt][ot][r] = zr ? 0.f : fmaf(a1, scale, b2b);
                acc[2][pt][ot][r] = zc ? 0.f : fmaf(a2, scale, b2b);
                acc[3][pt][ot][r] = fmaf(a3, scale, b2b);
            }
    }

    // upsample accumulation
    const char* up = (const char*)xupT;
    const char* wu = (const char*)wupT;
    int uBaseA[2];
#pragma unroll
    for (int pt = 0; pt < 2; ++pt)
        uBaseA[pt] = (((b * 28 + qy) * 16 + lg) * 32 + (pt * 16 + l15)) * 16;
    for (int k0 = 0; k0 < 128; k0 += 32) {
        bf16x8 wb[4][2];
#pragma unroll
        for (int p = 0; p < 4; ++p)
#pragma unroll
            for (int ot = 0; ot < 2; ++ot)
                wb[p][ot] = *(const bf16x8*)(wu + (bBase + p * 32768 + k0 * 256 + ot * 256));
#pragma unroll
        for (int pt = 0; pt < 2; ++pt) {
            bf16x8 aU = *(const bf16x8*)(up + (uBaseA[pt] + k0 * 64));
#pragma unroll
            for (int p = 0; p < 4; ++p)
#pragma unroll
                for (int ot = 0; ot < 2; ++ot)
                    acc[p][pt][ot] = MFMA(aU, wb[p][ot], acc[p][pt][ot]);
        }
    }

    // relu + store (one output quad-row per wave)
#pragma unroll
    for (int pt = 0; pt < 2; ++pt) {
        int qx0 = pt * 16 + lg * 4;
        if (qx0 >= 28) continue;
#pragma unroll
        for (int ot = 0; ot < 2; ++ot) {
            int o = wo * 32 + ot * 16 + l15;
            size_t base = ((size_t)(b * NO + o) * OH + 2 * qy) * OH + 2 * qx0;
#pragma unroll
            for (int r = 0; r < 4; ++r) {
                float2 v0 = { fmaxf(acc[0][pt][ot][r], 0.f), fmaxf(acc[1][pt][ot][r], 0.f) };
                float2 v1 = { fmaxf(acc[2][pt][ot][r], 0.f), fmaxf(acc[3][pt][ot][r], 0.f) };
                *reinterpret_cast<float2*>(&out[base + 2 * r]) = v0;
                *reinterpret_cast<float2*>(&out[base + OH + 2 * r]) = v1;
            }
        }
    }
}

// ---------------------------------------------------------------------------
extern "C" void kernel_launch(void* const* d_in, const int* in_sizes, int n_in,
                              void* d_out, int out_size, void* d_ws, size_t ws_size,
                              hipStream_t stream)
{
    const float* x     = (const float*)d_in[0];
    const float* w2    = (const float*)d_in[1];
    const float* w1    = (const float*)d_in[2];
    const float* wup   = (const float*)d_in[3];
    const float* b1a   = (const float*)d_in[4];
    const float* b1b   = (const float*)d_in[5];
    const float* b2a   = (const float*)d_in[6];
    const float* b2b   = (const float*)d_in[7];
    const float* scale = (const float*)d_in[8];

    char* ws = (char*)d_ws;
    u16* xT2   = (u16*)(ws);                 // 15,728,640 B
    u16* r1T   = (u16*)(ws + 15728640);      // 15,728,640 B
    u16* xupT  = (u16*)(ws + 31457280);      //  7,340,032 B
    u16* wT2   = (u16*)(ws + 38797312);      //  1,179,648 B
    u16* wc2T  = (u16*)(ws + 39976960);      //    589,824 B
    u16* wupT  = (u16*)(ws + 40566784);      //    131,072 B
    float* rng = (float*)(ws + 40697856);    //     32,768 B
    float* out = (float*)d_out;

    hipLaunchKernelGGL(k_prep, dim3(2192), dim3(256), 0, stream,
                       x, b1a, xT2, rng, w2, w1, wup, wT2, wc2T, wupT, (uint4*)r1T);
    hipLaunchKernelGGL(k_conv1x, dim3(1344), dim3(512), 0, stream,
                       xT2, wT2, b1b, b2a, r1T, x, rng, b1a, xupT);
    hipLaunchKernelGGL(k_conv2_mfma, dim3(448), dim3(512), 0, stream,
                       r1T, xupT, wc2T, wupT, scale, b2b, out);
}

// Round 23
// 92.642 us; speedup vs baseline: 1.1517x; 1.1517x over previous
//
#include <hip/hip_runtime.h>

#define NB 32      // batch
#define NC 256     // planes
#define NO 128     // inplanes (output channels)
#define HH 28
#define HW 784     // 28*28
#define OH 56

typedef unsigned short u16;
typedef __attribute__((ext_vector_type(8))) short bf16x8;
typedef __attribute__((ext_vector_type(4))) float f32x4;
typedef __attribute__((ext_vector_type(8))) unsigned short u16x8;

#define MFMA(A,B,C) __builtin_amdgcn_mfma_f32_16x16x32_bf16(A,B,C,0,0,0)

__device__ __forceinline__ u16 f2bf(float f) {
    unsigned u = __float_as_uint(f);
    unsigned r = (u + 0x7fffu + ((u >> 16) & 1u)) >> 16;
    return (u16)r;
}

// ---------------------------------------------------------------------------
// k_prep: grid-concat of prep_x ([0,1024)) and misc ([1024,2192)).
//  prep_x: fused x-pack + per-channel range (block = (b, cb), 25KB LDS),
//          x loads vectorized float4.
//  misc:   weight packs (wT2/wc2T/wupT) + r1T pad-ring zero.
// ---------------------------------------------------------------------------
__global__ __launch_bounds__(256) void k_prep(
    const float* __restrict__ x, const float* __restrict__ pb1a,
    u16* __restrict__ xT2, float* __restrict__ rng,
    const float* __restrict__ w2, const float* __restrict__ w1,
    const float* __restrict__ wup,
    u16* __restrict__ wT2, u16* __restrict__ wc2T,
    u16* __restrict__ wupT, uint4* __restrict__ r1T4)
{
    __shared__ float sx[8][HW];        // 25088 B (prep_x blocks only)
    __shared__ float smx[8][4], smn[8][4];

    if (blockIdx.x >= 1024) {
        int blk = blockIdx.x - 1024;
        if (blk < 288) {
            int g = blk * 256 + threadIdx.x;          // 9*32*256
            int o = g & 255;
            int cb = (g >> 8) & 31;
            int tap = g >> 13;
            int u = 2 - tap / 3, v = 2 - tap % 3;
            u16x8 out;
#pragma unroll
            for (int ci = 0; ci < 8; ++ci) {
                int c = cb * 8 + ci;
                out[ci] = f2bf(w2[((c * NC + o) * 3 + u) * 3 + v]);
            }
            *(u16x8*)(wT2 + (size_t)g * 8) = out;
        } else if (blk < 432) {
            const int taps[9] = {0, 2, 6, 8, 1, 7, 3, 5, 4};
            int g = (blk - 288) * 256 + threadIdx.x;  // 9*32*128
            int o = g & 127;
            int cb = (g >> 7) & 31;
            int s = g >> 12;
            int tap = taps[s];
            u16x8 out;
#pragma unroll
            for (int ci = 0; ci < 8; ++ci) {
                int c = cb * 8 + ci;
                out[ci] = f2bf(w1[(c * NO + o) * 9 + tap]);
            }
            *(u16x8*)(wc2T + (size_t)g * 8) = out;
        } else if (blk < 464) {
            int g = (blk - 432) * 256 + threadIdx.x;  // 4*16*128
            int o = g & 127;
            int kb = (g >> 7) & 15;
            int p = g >> 11;
            u16x8 out;
#pragma unroll
            for (int ki = 0; ki < 8; ++ki) {
                int k = kb * 8 + ki;
                out[ki] = f2bf(wup[(k * NO + o) * 4 + p]);
            }
            *(u16x8*)(wupT + (size_t)g * 8) = out;
        } else {
            int g = (blk - 464) * 256 + threadIdx.x;  // 180224
            int i = g % 176;
            int bc = g / 176;                  // b*32 + cb
            int b = bc >> 5, cb = bc & 31;
            int row, cx;
            if (i < 32)      { row = 0;  cx = i; }
            else if (i < 64) { row = 29; cx = i - 32; }
            else {
                int j = i - 64;
                row = 1 + (j >> 2);
                int k = j & 3;
                cx = (k == 0) ? 0 : 28 + k;    // 0,29,30,31
            }
            r1T4[((b * 30 + row) * 32 + cb) * 32 + cx] = make_uint4(0, 0, 0, 0);
        }
        return;
    }

    // ---- prep_x (float4 loads: 196 float4 per channel)
    int t = threadIdx.x;
    int b = blockIdx.x >> 5, cb = blockIdx.x & 31;
    float b1a = pb1a[0];
    const float* xb = x + ((size_t)b * NC + cb * 8) * HW;

    float mx[8], mn[8];
#pragma unroll
    for (int ci = 0; ci < 8; ++ci) { mx[ci] = -1e30f; mn[ci] = 1e30f; }
#pragma unroll
    for (int ci = 0; ci < 8; ++ci) {
        const float4* xb4 = (const float4*)(xb + ci * HW);
        float4* sx4 = (float4*)sx[ci];
        if (t < 196) {
            float4 v = xb4[t];
            sx4[t] = v;
            mx[ci] = fmaxf(fmaxf(v.x, v.y), fmaxf(v.z, v.w));
            mn[ci] = fminf(fminf(v.x, v.y), fminf(v.z, v.w));
        }
    }
    int lane = t & 63, wv = t >> 6;
#pragma unroll
    for (int ci = 0; ci < 8; ++ci) {
        float a = mx[ci], i = mn[ci];
        for (int off = 32; off; off >>= 1) {
            a = fmaxf(a, __shfl_down(a, off, 64));
            i = fminf(i, __shfl_down(i, off, 64));
        }
        if (lane == 0) { smx[ci][wv] = a; smn[ci][wv] = i; }
    }
    __syncthreads();
    if (t < 8) {
        float a = fmaxf(fmaxf(smx[t][0], smx[t][1]), fmaxf(smx[t][2], smx[t][3]));
        float i = fminf(fminf(smn[t][0], smn[t][1]), fminf(smn[t][2], smn[t][3]));
        rng[b * NC + cb * 8 + t] = a - i;
    }
    for (int g = t; g < 960; g += 256) {
        int ry = g >> 5, cx = g & 31;
        int y = ry - 1, xx = cx - 1;
        bool valid = (y >= 0 && y < HH && xx >= 0 && xx < HH);
        u16x8 out;
#pragma unroll
        for (int ci = 0; ci < 8; ++ci) {
            float f = valid ? sx[ci][y * 28 + xx] + b1a : 0.f;
            out[ci] = f2bf(f);
        }
        *(u16x8*)(xT2 + ((((size_t)b * 30 + ry) * 32 + cb) * 32 + cx) * 8) = out;
    }
}

// ---------------------------------------------------------------------------
// k_conv1x: grid-concat of conv1 (blocks [0,448)) and pack_xup ([448,1344)).
// pack_xup blocks recompute the channel selection locally from rng (each
// block = one (b,qy); 256-thread stable-rank in LDS).
// ---------------------------------------------------------------------------
__global__ __launch_bounds__(512, 4) void k_conv1x(
    const u16* __restrict__ xT2, const u16* __restrict__ wT2,
    const float* __restrict__ pb1b, const float* __restrict__ pb2a,
    u16* __restrict__ r1T,
    const float* __restrict__ x, const float* __restrict__ rng,
    const float* __restrict__ pb1a, u16* __restrict__ xupT)
{
    __shared__ u16 sA[6 * 16 * 32 * 8];   // 49152 B (conv1); reused by pack_xup
    if (blockIdx.x >= 448) {
        // ---- pack_xup with local select: block = one (b, qy)
        int blk = blockIdx.x - 448;        // 896 = 32b * 28qy
        int tid = threadIdx.x;
        int b = blk / 28;
        int qy = blk - b * 28;
        float b1a = pb1a[0];

        float* srng = (float*)sA;          // 256 floats
        int* ssel = (int*)(sA + 2048);     // 128 ints

        if (tid < 256) srng[tid] = rng[b * NC + tid];
        __syncthreads();
        if (tid < 256) {
            float v = srng[tid];
            int rank = 0;
            for (int j = 0; j < NC; ++j) {
                float u = srng[j];
                rank += (u < v) || (u == v && j < tid);
            }
            if (rank >= NC / 2) ssel[rank - NC / 2] = tid;
        }
        __syncthreads();

        int cx = tid & 31;
        int kb = tid >> 5;
        bool valid = cx < 28;
        const float* xb = x + (size_t)b * NC * HW + qy * 28 + (valid ? cx : 0);
        u16x8 out;
#pragma unroll
        for (int ki = 0; ki < 8; ++ki) {
            int ch = ssel[kb * 8 + ki];
            float f = valid ? xb[ch * HW] + b1a : 0.f;
            out[ki] = f2bf(f);
        }
        size_t g = ((size_t)(b * 28 + qy) * 16 + kb) * 32 + cx;
        *(u16x8*)(xupT + g * 8) = out;
        return;
    }

    // ---- conv1 (frozen r19/r21 structure)
    int tid = threadIdx.x;
    int wave = tid >> 6, lane = tid & 63;
    int wpi = wave >> 2;
    int wo = wave & 3;
    int l15 = lane & 15, lg = lane >> 4;

    int idx = blockIdx.x;             // 448
    int b = idx / 14;
    int rem = idx - b * 14;
    int rg = rem >> 1;
    int og = rem & 1;
    int y0 = rg * 4;

    float b1b = pb1b[0], b2a = pb2a[0];

    int bOff[2];
#pragma unroll
    for (int ot = 0; ot < 2; ++ot)
        bOff[ot] = (lg * 256 + (og * 128 + wo * 32 + ot * 16 + l15)) * 16;

    f32x4 acc[4][2] = {};
    const char* wq = (const char*)wT2;
    const char* ap0 = (const char*)sA;
    const uint4* gx = (const uint4*)xT2;
    uint4* dst = (uint4*)sA;

    int aLane = (2 * wpi) * 8192 + lg * 512 + l15 * 16;

    for (int half = 0; half < 2; ++half) {
        if (half) __syncthreads();
#pragma unroll
        for (int i = 0; i < 6; ++i)
            dst[tid + i * 512] = gx[(b * 30 + y0 + i) * 1024 + half * 512 + tid];
        __syncthreads();

        for (int cc = 0; cc < 128; cc += 32) {
            int c0 = half * 128 + cc;
            int aBase = aLane + cc * 64;
#pragma unroll
            for (int dx = 0; dx < 3; ++dx) {
                bf16x8 w[3][2];
#pragma unroll
                for (int dy = 0; dy < 3; ++dy)
#pragma unroll
                    for (int ot = 0; ot < 2; ++ot)
                        w[dy][ot] = *(const bf16x8*)(wq +
                            (bOff[ot] + (dy * 3 + dx) * 131072 + c0 * 512));
                bf16x8 a[4][2];
#pragma unroll
                for (int r = 0; r < 4; ++r)
#pragma unroll
                    for (int h = 0; h < 2; ++h)
                        a[r][h] = *(const bf16x8*)(ap0 +
                            (aBase + r * 8192 + (h * 16 + dx) * 16));
#pragma unroll
                for (int dy = 0; dy < 3; ++dy)
#pragma unroll
                    for (int m = 0; m < 2; ++m)
#pragma unroll
                        for (int h = 0; h < 2; ++h)
#pragma unroll
                            for (int ot = 0; ot < 2; ++ot)
                                acc[m * 2 + h][ot] =
                                    MFMA(a[m + dy][h], w[dy][ot], acc[m * 2 + h][ot]);
            }
        }
    }

#pragma unroll
    for (int m = 0; m < 2; ++m)
#pragma unroll
        for (int h = 0; h < 2; ++h) {
            int y = y0 + 2 * wpi + m;
            int x0 = h * 16 + lg * 4;
            if (x0 >= 28) continue;
#pragma unroll
            for (int ot = 0; ot < 2; ++ot) {
                int o = og * 128 + wo * 32 + ot * 16 + l15;
                size_t base = ((((size_t)b * 30 + y + 1) * 32 + (o >> 3)) * 32 + (x0 + 1)) * 8 + (o & 7);
#pragma unroll
                for (int r = 0; r < 4; ++r) {
                    float f = fmaxf(acc[m * 2 + h][ot][r] + b1b, 0.f) + b2a;
                    r1T[base + (size_t)r * 8] = f2bf(f);
                }
            }
        }
}

// ---------------------------------------------------------------------------
// conv2 + upsample via MFMA, A-slab in LDS (r21 measured-good version:
// 224 blocks, full 128 o, 80KB 5-row slab, 2 blocks/CU).
// ---------------------------------------------------------------------------
__global__ __launch_bounds__(512, 2) void k_conv2_mfma(
    const u16* __restrict__ r1T, const u16* __restrict__ xupT,
    const u16* __restrict__ wc2T, const u16* __restrict__ wupT,
    const float* __restrict__ pscale, const float* __restrict__ pb2b,
    float* __restrict__ out)
{
    __shared__ uint4 sA2[5120];       // 81920 B
    int tid = threadIdx.x;
    int wave = tid >> 6, lane = tid & 63;
    int wpi = wave >> 2;
    int wo = wave & 3;
    int l15 = lane & 15, lg = lane >> 4;

    int b = blockIdx.x / 7;
    int rg = blockIdx.x - b * 7;
    int y0 = rg * 4;

    float scale = pscale[0], b2b = pb2b[0];

    {
        const uint4* src = (const uint4*)(r1T + (size_t)(b * 30 + y0) * 8192);
#pragma unroll
        for (int i = 0; i < 10; ++i)
            sA2[tid + i * 512] = src[tid + i * 512];
    }
    __syncthreads();

    f32x4 acc[4][4][2] = {};

    const char* sp = (const char*)sA2;
    const char* wp = (const char*)wc2T;

    int aBase[4];
#pragma unroll
    for (int pt = 0; pt < 4; ++pt) {
        int rel = 2 * wpi + (pt >> 1) + 1;
        int qt = pt & 1;
        aBase[pt] = ((rel * 32 + lg) * 32 + (qt * 16 + l15 + 1)) * 16;
    }
    int bBase = (lg * 128 + wo * 32 + l15) * 16;

    for (int c0 = 0; c0 < 256; c0 += 32) {
        bf16x8 w[9][2];
#pragma unroll
        for (int s = 0; s < 9; ++s)
#pragma unroll
            for (int ot = 0; ot < 2; ++ot)
                w[s][ot] = *(const bf16x8*)(wp + (bBase + s * 65536 + c0 * 256 + ot * 256));
#pragma unroll
        for (int pt = 0; pt < 4; ++pt) {
            const char* ap = sp + (aBase[pt] + c0 * 64);
            bf16x8 aD = *(const bf16x8*)(ap);
            bf16x8 aC = *(const bf16x8*)(ap - 16);
            bf16x8 aB = *(const bf16x8*)(ap - 16384);
            bf16x8 aA = *(const bf16x8*)(ap - 16400);
#pragma unroll
            for (int ot = 0; ot < 2; ++ot) {
                acc[0][pt][ot] = MFMA(aD, w[0][ot], acc[0][pt][ot]);
                acc[0][pt][ot] = MFMA(aC, w[1][ot], acc[0][pt][ot]);
                acc[0][pt][ot] = MFMA(aB, w[2][ot], acc[0][pt][ot]);
                acc[0][pt][ot] = MFMA(aA, w[3][ot], acc[0][pt][ot]);
                acc[1][pt][ot] = MFMA(aD, w[4][ot], acc[1][pt][ot]);
                acc[1][pt][ot] = MFMA(aB, w[5][ot], acc[1][pt][ot]);
                acc[2][pt][ot] = MFMA(aD, w[6][ot], acc[2][pt][ot]);
                acc[2][pt][ot] = MFMA(aC, w[7][ot], acc[2][pt][ot]);
                acc[3][pt][ot] = MFMA(aD, w[8][ot], acc[3][pt][ot]);
            }
        }
    }

#pragma unroll
    for (int pt = 0; pt < 4; ++pt) {
        int qy = y0 + 2 * wpi + (pt >> 1);
        int qt = pt & 1;
        int qx0 = qt * 16 + lg * 4;
        bool zr = (qy == 0);
#pragma unroll
        for (int ot = 0; ot < 2; ++ot)
#pragma unroll
            for (int r = 0; r < 4; ++r) {
                bool zc = (qx0 + r == 0);
                float a0 = acc[0][pt][ot][r], a1 = acc[1][pt][ot][r];
                float a2 = acc[2][pt][ot][r], a3 = acc[3][pt][ot][r];
                acc[0][pt][ot][r] = (zr || zc) ? 0.f : fmaf(a0, scale, b2b);
                acc[1][pt][ot][r] = zr ? 0.f : fmaf(a1, scale, b2b);
                acc[2][pt][ot][r] = zc ? 0.f : fmaf(a2, scale, b2b);
                acc[3][pt][ot][r] = fmaf(a3, scale, b2b);
            }
    }

    const char* up = (const char*)xupT;
    const char* wu = (const char*)wupT;
    int uBaseA[4];
#pragma unroll
    for (int pt = 0; pt < 4; ++pt) {
        int qy = y0 + 2 * wpi + (pt >> 1);
        int qt = pt & 1;
        uBaseA[pt] = (((b * 28 + qy) * 16 + lg) * 32 + (qt * 16 + l15)) * 16;
    }
    for (int k0 = 0; k0 < 128; k0 += 32) {
        bf16x8 wb[4][2];
#pragma unroll
        for (int p = 0; p < 4; ++p)
#pragma unroll
            for (int ot = 0; ot < 2; ++ot)
                wb[p][ot] = *(const bf16x8*)(wu + (bBase + p * 32768 + k0 * 256 + ot * 256));
#pragma unroll
        for (int pt = 0; pt < 4; ++pt) {
            bf16x8 aU = *(const bf16x8*)(up + (uBaseA[pt] + k0 * 64));
#pragma unroll
            for (int p = 0; p < 4; ++p)
#pragma unroll
                for (int ot = 0; ot < 2; ++ot)
                    acc[p][pt][ot] = MFMA(aU, wb[p][ot], acc[p][pt][ot]);
        }
    }

#pragma unroll
    for (int pt = 0; pt < 4; ++pt) {
        int qy = y0 + 2 * wpi + (pt >> 1);
        int qt = pt & 1;
        int qx0 = qt * 16 + lg * 4;
        if (qx0 >= 28) continue;
#pragma unroll
        for (int ot = 0; ot < 2; ++ot) {
            int o = wo * 32 + ot * 16 + l15;
            size_t base = ((size_t)(b * NO + o) * OH + 2 * qy) * OH + 2 * qx0;
#pragma unroll
            for (int r = 0; r < 4; ++r) {
                float2 v0 = { fmaxf(acc[0][pt][ot][r], 0.f), fmaxf(acc[1][pt][ot][r], 0.f) };
                float2 v1 = { fmaxf(acc[2][pt][ot][r], 0.f), fmaxf(acc[3][pt][ot][r], 0.f) };
                *reinterpret_cast<float2*>(&out[base + 2 * r]) = v0;
                *reinterpret_cast<float2*>(&out[base + OH + 2 * r]) = v1;
            }
        }
    }
}

// ---------------------------------------------------------------------------
extern "C" void kernel_launch(void* const* d_in, const int* in_sizes, int n_in,
                              void* d_out, int out_size, void* d_ws, size_t ws_size,
                              hipStream_t stream)
{
    const float* x     = (const float*)d_in[0];
    const float* w2    = (const float*)d_in[1];
    const float* w1    = (const float*)d_in[2];
    const float* wup   = (const float*)d_in[3];
    const float* b1a   = (const float*)d_in[4];
    const float* b1b   = (const float*)d_in[5];
    const float* b2a   = (const float*)d_in[6];
    const float* b2b   = (const float*)d_in[7];
    const float* scale = (const float*)d_in[8];

    char* ws = (char*)d_ws;
    u16* xT2   = (u16*)(ws);                 // 15,728,640 B
    u16* r1T   = (u16*)(ws + 15728640);      // 15,728,640 B
    u16* xupT  = (u16*)(ws + 31457280);      //  7,340,032 B
    u16* wT2   = (u16*)(ws + 38797312);      //  1,179,648 B
    u16* wc2T  = (u16*)(ws + 39976960);      //    589,824 B
    u16* wupT  = (u16*)(ws + 40566784);      //    131,072 B
    float* rng = (float*)(ws + 40697856);    //     32,768 B
    float* out = (float*)d_out;

    hipLaunchKernelGGL(k_prep, dim3(2192), dim3(256), 0, stream,
                       x, b1a, xT2, rng, w2, w1, wup, wT2, wc2T, wupT, (uint4*)r1T);
    hipLaunchKernelGGL(k_conv1x, dim3(1344), dim3(512), 0, stream,
                       xT2, wT2, b1b, b2a, r1T, x, rng, b1a, xupT);
    hipLaunchKernelGGL(k_conv2_mfma, dim3(NB * 7), dim3(512), 0, stream,
                       r1T, xupT, wc2T, wupT, scale, b2b, out);
}

// Round 24
// 92.472 us; speedup vs baseline: 1.1538x; 1.0018x over previous
//
#include <hip/hip_runtime.h>

#define NB 32      // batch
#define NC 256     // planes
#define NO 128     // inplanes (output channels)
#define HH 28
#define HW 784     // 28*28
#define OH 56

typedef unsigned short u16;
typedef unsigned int u32;
typedef __attribute__((ext_vector_type(8))) short bf16x8;
typedef __attribute__((ext_vector_type(4))) float f32x4;
typedef __attribute__((ext_vector_type(8))) unsigned short u16x8;

#define MFMA(A,B,C) __builtin_amdgcn_mfma_f32_16x16x32_bf16(A,B,C,0,0,0)

typedef __attribute__((address_space(3))) u32 lds_u32;
typedef const __attribute__((address_space(1))) u32 glb_u32;

// async 16B global->LDS (direct, no VGPR round-trip)
__device__ __forceinline__ void gld_lds16(const void* g, void* l) {
    __builtin_amdgcn_global_load_lds((glb_u32*)g, (lds_u32*)l, 16, 0, 0);
}

__device__ __forceinline__ u16 f2bf(float f) {
    unsigned u = __float_as_uint(f);
    unsigned r = (u + 0x7fffu + ((u >> 16) & 1u)) >> 16;
    return (u16)r;
}

// ---------------------------------------------------------------------------
// k_prep: grid-concat of prep_x ([0,1024)) and misc ([1024,2192)).
// (frozen from r21/r23)
// ---------------------------------------------------------------------------
__global__ __launch_bounds__(256) void k_prep(
    const float* __restrict__ x, const float* __restrict__ pb1a,
    u16* __restrict__ xT2, float* __restrict__ rng,
    const float* __restrict__ w2, const float* __restrict__ w1,
    const float* __restrict__ wup,
    u16* __restrict__ wT2, u16* __restrict__ wc2T,
    u16* __restrict__ wupT, uint4* __restrict__ r1T4)
{
    __shared__ float sx[8][HW];        // 25088 B (prep_x blocks only)
    __shared__ float smx[8][4], smn[8][4];

    if (blockIdx.x >= 1024) {
        int blk = blockIdx.x - 1024;
        if (blk < 288) {
            int g = blk * 256 + threadIdx.x;          // 9*32*256
            int o = g & 255;
            int cb = (g >> 8) & 31;
            int tap = g >> 13;
            int u = 2 - tap / 3, v = 2 - tap % 3;
            u16x8 out;
#pragma unroll
            for (int ci = 0; ci < 8; ++ci) {
                int c = cb * 8 + ci;
                out[ci] = f2bf(w2[((c * NC + o) * 3 + u) * 3 + v]);
            }
            *(u16x8*)(wT2 + (size_t)g * 8) = out;
        } else if (blk < 432) {
            const int taps[9] = {0, 2, 6, 8, 1, 7, 3, 5, 4};
            int g = (blk - 288) * 256 + threadIdx.x;  // 9*32*128
            int o = g & 127;
            int cb = (g >> 7) & 31;
            int s = g >> 12;
            int tap = taps[s];
            u16x8 out;
#pragma unroll
            for (int ci = 0; ci < 8; ++ci) {
                int c = cb * 8 + ci;
                out[ci] = f2bf(w1[(c * NO + o) * 9 + tap]);
            }
            *(u16x8*)(wc2T + (size_t)g * 8) = out;
        } else if (blk < 464) {
            int g = (blk - 432) * 256 + threadIdx.x;  // 4*16*128
            int o = g & 127;
            int kb = (g >> 7) & 15;
            int p = g >> 11;
            u16x8 out;
#pragma unroll
            for (int ki = 0; ki < 8; ++ki) {
                int k = kb * 8 + ki;
                out[ki] = f2bf(wup[(k * NO + o) * 4 + p]);
            }
            *(u16x8*)(wupT + (size_t)g * 8) = out;
        } else {
            int g = (blk - 464) * 256 + threadIdx.x;  // 180224
            int i = g % 176;
            int bc = g / 176;                  // b*32 + cb
            int b = bc >> 5, cb = bc & 31;
            int row, cx;
            if (i < 32)      { row = 0;  cx = i; }
            else if (i < 64) { row = 29; cx = i - 32; }
            else {
                int j = i - 64;
                row = 1 + (j >> 2);
                int k = j & 3;
                cx = (k == 0) ? 0 : 28 + k;    // 0,29,30,31
            }
            r1T4[((b * 30 + row) * 32 + cb) * 32 + cx] = make_uint4(0, 0, 0, 0);
        }
        return;
    }

    // ---- prep_x (float4 loads: 196 float4 per channel)
    int t = threadIdx.x;
    int b = blockIdx.x >> 5, cb = blockIdx.x & 31;
    float b1a = pb1a[0];
    const float* xb = x + ((size_t)b * NC + cb * 8) * HW;

    float mx[8], mn[8];
#pragma unroll
    for (int ci = 0; ci < 8; ++ci) { mx[ci] = -1e30f; mn[ci] = 1e30f; }
#pragma unroll
    for (int ci = 0; ci < 8; ++ci) {
        const float4* xb4 = (const float4*)(xb + ci * HW);
        float4* sx4 = (float4*)sx[ci];
        if (t < 196) {
            float4 v = xb4[t];
            sx4[t] = v;
            mx[ci] = fmaxf(fmaxf(v.x, v.y), fmaxf(v.z, v.w));
            mn[ci] = fminf(fminf(v.x, v.y), fminf(v.z, v.w));
        }
    }
    int lane = t & 63, wv = t >> 6;
#pragma unroll
    for (int ci = 0; ci < 8; ++ci) {
        float a = mx[ci], i = mn[ci];
        for (int off = 32; off; off >>= 1) {
            a = fmaxf(a, __shfl_down(a, off, 64));
            i = fminf(i, __shfl_down(i, off, 64));
        }
        if (lane == 0) { smx[ci][wv] = a; smn[ci][wv] = i; }
    }
    __syncthreads();
    if (t < 8) {
        float a = fmaxf(fmaxf(smx[t][0], smx[t][1]), fmaxf(smx[t][2], smx[t][3]));
        float i = fminf(fminf(smn[t][0], smn[t][1]), fminf(smn[t][2], smn[t][3]));
        rng[b * NC + cb * 8 + t] = a - i;
    }
    for (int g = t; g < 960; g += 256) {
        int ry = g >> 5, cx = g & 31;
        int y = ry - 1, xx = cx - 1;
        bool valid = (y >= 0 && y < HH && xx >= 0 && xx < HH);
        u16x8 out;
#pragma unroll
        for (int ci = 0; ci < 8; ++ci) {
            float f = valid ? sx[ci][y * 28 + xx] + b1a : 0.f;
            out[ci] = f2bf(f);
        }
        *(u16x8*)(xT2 + ((((size_t)b * 30 + ry) * 32 + cb) * 32 + cx) * 8) = out;
    }
}

// ---------------------------------------------------------------------------
// k_conv1x: grid-concat of conv1 (blocks [0,448)) and pack_xup ([448,1344)).
// conv1 A-slab staging now via global_load_lds (async direct-to-LDS, 16B).
// ---------------------------------------------------------------------------
__global__ __launch_bounds__(512, 4) void k_conv1x(
    const u16* __restrict__ xT2, const u16* __restrict__ wT2,
    const float* __restrict__ pb1b, const float* __restrict__ pb2a,
    u16* __restrict__ r1T,
    const float* __restrict__ x, const float* __restrict__ rng,
    const float* __restrict__ pb1a, u16* __restrict__ xupT)
{
    __shared__ u16 sA[6 * 16 * 32 * 8];   // 49152 B (conv1); reused by pack_xup
    if (blockIdx.x >= 448) {
        // ---- pack_xup with local select: block = one (b, qy)
        int blk = blockIdx.x - 448;        // 896 = 32b * 28qy
        int tid = threadIdx.x;
        int b = blk / 28;
        int qy = blk - b * 28;
        float b1a = pb1a[0];

        float* srng = (float*)sA;          // 256 floats
        int* ssel = (int*)(sA + 2048);     // 128 ints

        if (tid < 256) srng[tid] = rng[b * NC + tid];
        __syncthreads();
        if (tid < 256) {
            float v = srng[tid];
            int rank = 0;
            for (int j = 0; j < NC; ++j) {
                float u = srng[j];
                rank += (u < v) || (u == v && j < tid);
            }
            if (rank >= NC / 2) ssel[rank - NC / 2] = tid;
        }
        __syncthreads();

        int cx = tid & 31;
        int kb = tid >> 5;
        bool valid = cx < 28;
        const float* xb = x + (size_t)b * NC * HW + qy * 28 + (valid ? cx : 0);
        u16x8 out;
#pragma unroll
        for (int ki = 0; ki < 8; ++ki) {
            int ch = ssel[kb * 8 + ki];
            float f = valid ? xb[ch * HW] + b1a : 0.f;
            out[ki] = f2bf(f);
        }
        size_t g = ((size_t)(b * 28 + qy) * 16 + kb) * 32 + cx;
        *(u16x8*)(xupT + g * 8) = out;
        return;
    }

    // ---- conv1 (r19/r21 structure; staging via global_load_lds)
    int tid = threadIdx.x;
    int wave = tid >> 6, lane = tid & 63;
    int wpi = wave >> 2;
    int wo = wave & 3;
    int l15 = lane & 15, lg = lane >> 4;

    int idx = blockIdx.x;             // 448
    int b = idx / 14;
    int rem = idx - b * 14;
    int rg = rem >> 1;
    int og = rem & 1;
    int y0 = rg * 4;

    float b1b = pb1b[0], b2a = pb2a[0];

    int bOff[2];
#pragma unroll
    for (int ot = 0; ot < 2; ++ot)
        bOff[ot] = (lg * 256 + (og * 128 + wo * 32 + ot * 16 + l15)) * 16;

    f32x4 acc[4][2] = {};
    const char* wq = (const char*)wT2;
    const char* ap0 = (const char*)sA;
    const uint4* gx = (const uint4*)xT2;
    uint4* dst = (uint4*)sA;

    int aLane = (2 * wpi) * 8192 + lg * 512 + l15 * 16;

    for (int half = 0; half < 2; ++half) {
        if (half) __syncthreads();    // all reads of sA done before overwrite
#pragma unroll
        for (int i = 0; i < 6; ++i)
            gld_lds16(gx + (b * 30 + y0 + i) * 1024 + half * 512 + tid,
                      dst + tid + i * 512);
        __syncthreads();

        for (int cc = 0; cc < 128; cc += 32) {
            int c0 = half * 128 + cc;
            int aBase = aLane + cc * 64;
#pragma unroll
            for (int dx = 0; dx < 3; ++dx) {
                bf16x8 w[3][2];
#pragma unroll
                for (int dy = 0; dy < 3; ++dy)
#pragma unroll
                    for (int ot = 0; ot < 2; ++ot)
                        w[dy][ot] = *(const bf16x8*)(wq +
                            (bOff[ot] + (dy * 3 + dx) * 131072 + c0 * 512));
                bf16x8 a[4][2];
#pragma unroll
                for (int r = 0; r < 4; ++r)
#pragma unroll
                    for (int h = 0; h < 2; ++h)
                        a[r][h] = *(const bf16x8*)(ap0 +
                            (aBase + r * 8192 + (h * 16 + dx) * 16));
#pragma unroll
                for (int dy = 0; dy < 3; ++dy)
#pragma unroll
                    for (int m = 0; m < 2; ++m)
#pragma unroll
                        for (int h = 0; h < 2; ++h)
#pragma unroll
                            for (int ot = 0; ot < 2; ++ot)
                                acc[m * 2 + h][ot] =
                                    MFMA(a[m + dy][h], w[dy][ot], acc[m * 2 + h][ot]);
            }
        }
    }

#pragma unroll
    for (int m = 0; m < 2; ++m)
#pragma unroll
        for (int h = 0; h < 2; ++h) {
            int y = y0 + 2 * wpi + m;
            int x0 = h * 16 + lg * 4;
            if (x0 >= 28) continue;
#pragma unroll
            for (int ot = 0; ot < 2; ++ot) {
                int o = og * 128 + wo * 32 + ot * 16 + l15;
                size_t base = ((((size_t)b * 30 + y + 1) * 32 + (o >> 3)) * 32 + (x0 + 1)) * 8 + (o & 7);
#pragma unroll
                for (int r = 0; r < 4; ++r) {
                    float f = fmaxf(acc[m * 2 + h][ot][r] + b1b, 0.f) + b2a;
                    r1T[base + (size_t)r * 8] = f2bf(f);
                }
            }
        }
}

// ---------------------------------------------------------------------------
// conv2 + upsample via MFMA, A-slab in LDS (r21 structure; staging via
// global_load_lds). 224 blocks, full 128 o, 80KB 5-row slab, 2 blocks/CU.
// ---------------------------------------------------------------------------
__global__ __launch_bounds__(512, 2) void k_conv2_mfma(
    const u16* __restrict__ r1T, const u16* __restrict__ xupT,
    const u16* __restrict__ wc2T, const u16* __restrict__ wupT,
    const float* __restrict__ pscale, const float* __restrict__ pb2b,
    float* __restrict__ out)
{
    __shared__ uint4 sA2[5120];       // 81920 B
    int tid = threadIdx.x;
    int wave = tid >> 6, lane = tid & 63;
    int wpi = wave >> 2;
    int wo = wave & 3;
    int l15 = lane & 15, lg = lane >> 4;

    int b = blockIdx.x / 7;
    int rg = blockIdx.x - b * 7;
    int y0 = rg * 4;

    float scale = pscale[0], b2b = pb2b[0];

    {
        const uint4* src = (const uint4*)(r1T + (size_t)(b * 30 + y0) * 8192);
#pragma unroll
        for (int i = 0; i < 10; ++i)
            gld_lds16(src + tid + i * 512, sA2 + tid + i * 512);
    }
    __syncthreads();

    f32x4 acc[4][4][2] = {};

    const char* sp = (const char*)sA2;
    const char* wp = (const char*)wc2T;

    int aBase[4];
#pragma unroll
    for (int pt = 0; pt < 4; ++pt) {
        int rel = 2 * wpi + (pt >> 1) + 1;
        int qt = pt & 1;
        aBase[pt] = ((rel * 32 + lg) * 32 + (qt * 16 + l15 + 1)) * 16;
    }
    int bBase = (lg * 128 + wo * 32 + l15) * 16;

    for (int c0 = 0; c0 < 256; c0 += 32) {
        bf16x8 w[9][2];
#pragma unroll
        for (int s = 0; s < 9; ++s)
#pragma unroll
            for (int ot = 0; ot < 2; ++ot)
                w[s][ot] = *(const bf16x8*)(wp + (bBase + s * 65536 + c0 * 256 + ot * 256));
#pragma unroll
        for (int pt = 0; pt < 4; ++pt) {
            const char* ap = sp + (aBase[pt] + c0 * 64);
            bf16x8 aD = *(const bf16x8*)(ap);
            bf16x8 aC = *(const bf16x8*)(ap - 16);
            bf16x8 aB = *(const bf16x8*)(ap - 16384);
            bf16x8 aA = *(const bf16x8*)(ap - 16400);
#pragma unroll
            for (int ot = 0; ot < 2; ++ot) {
                acc[0][pt][ot] = MFMA(aD, w[0][ot], acc[0][pt][ot]);
                acc[0][pt][ot] = MFMA(aC, w[1][ot], acc[0][pt][ot]);
                acc[0][pt][ot] = MFMA(aB, w[2][ot], acc[0][pt][ot]);
                acc[0][pt][ot] = MFMA(aA, w[3][ot], acc[0][pt][ot]);
                acc[1][pt][ot] = MFMA(aD, w[4][ot], acc[1][pt][ot]);
                acc[1][pt][ot] = MFMA(aB, w[5][ot], acc[1][pt][ot]);
                acc[2][pt][ot] = MFMA(aD, w[6][ot], acc[2][pt][ot]);
                acc[2][pt][ot] = MFMA(aC, w[7][ot], acc[2][pt][ot]);
                acc[3][pt][ot] = MFMA(aD, w[8][ot], acc[3][pt][ot]);
            }
        }
    }

#pragma unroll
    for (int pt = 0; pt < 4; ++pt) {
        int qy = y0 + 2 * wpi + (pt >> 1);
        int qt = pt & 1;
        int qx0 = qt * 16 + lg * 4;
        bool zr = (qy == 0);
#pragma unroll
        for (int ot = 0; ot < 2; ++ot)
#pragma unroll
            for (int r = 0; r < 4; ++r) {
                bool zc = (qx0 + r == 0);
                float a0 = acc[0][pt][ot][r], a1 = acc[1][pt][ot][r];
                float a2 = acc[2][pt][ot][r], a3 = acc[3][pt][ot][r];
                acc[0][pt][ot][r] = (zr || zc) ? 0.f : fmaf(a0, scale, b2b);
                acc[1][pt][ot][r] = zr ? 0.f : fmaf(a1, scale, b2b);
                acc[2][pt][ot][r] = zc ? 0.f : fmaf(a2, scale, b2b);
                acc[3][pt][ot][r] = fmaf(a3, scale, b2b);
            }
    }

    const char* up = (const char*)xupT;
    const char* wu = (const char*)wupT;
    int uBaseA[4];
#pragma unroll
    for (int pt = 0; pt < 4; ++pt) {
        int qy = y0 + 2 * wpi + (pt >> 1);
        int qt = pt & 1;
        uBaseA[pt] = (((b * 28 + qy) * 16 + lg) * 32 + (qt * 16 + l15)) * 16;
    }
    for (int k0 = 0; k0 < 128; k0 += 32) {
        bf16x8 wb[4][2];
#pragma unroll
        for (int p = 0; p < 4; ++p)
#pragma unroll
            for (int ot = 0; ot < 2; ++ot)
                wb[p][ot] = *(const bf16x8*)(wu + (bBase + p * 32768 + k0 * 256 + ot * 256));
#pragma unroll
        for (int pt = 0; pt < 4; ++pt) {
            bf16x8 aU = *(const bf16x8*)(up + (uBaseA[pt] + k0 * 64));
#pragma unroll
            for (int p = 0; p < 4; ++p)
#pragma unroll
                for (int ot = 0; ot < 2; ++ot)
                    acc[p][pt][ot] = MFMA(aU, wb[p][ot], acc[p][pt][ot]);
        }
    }

#pragma unroll
    for (int pt = 0; pt < 4; ++pt) {
        int qy = y0 + 2 * wpi + (pt >> 1);
        int qt = pt & 1;
        int qx0 = qt * 16 + lg * 4;
        if (qx0 >= 28) continue;
#pragma unroll
        for (int ot = 0; ot < 2; ++ot) {
            int o = wo * 32 + ot * 16 + l15;
            size_t base = ((size_t)(b * NO + o) * OH + 2 * qy) * OH + 2 * qx0;
#pragma unroll
            for (int r = 0; r < 4; ++r) {
                float2 v0 = { fmaxf(acc[0][pt][ot][r], 0.f), fmaxf(acc[1][pt][ot][r], 0.f) };
                float2 v1 = { fmaxf(acc[2][pt][ot][r], 0.f), fmaxf(acc[3][pt][ot][r], 0.f) };
                *reinterpret_cast<float2*>(&out[base + 2 * r]) = v0;
                *reinterpret_cast<float2*>(&out[base + OH + 2 * r]) = v1;
            }
        }
    }
}

// ---------------------------------------------------------------------------
extern "C" void kernel_launch(void* const* d_in, const int* in_sizes, int n_in,
                              void* d_out, int out_size, void* d_ws, size_t ws_size,
                              hipStream_t stream)
{
    const float* x     = (const float*)d_in[0];
    const float* w2    = (const float*)d_in[1];
    const float* w1    = (const float*)d_in[2];
    const float* wup   = (const float*)d_in[3];
    const float* b1a   = (const float*)d_in[4];
    const float* b1b   = (const float*)d_in[5];
    const float* b2a   = (const float*)d_in[6];
    const float* b2b   = (const float*)d_in[7];
    const float* scale = (const float*)d_in[8];

    char* ws = (char*)d_ws;
    u16* xT2   = (u16*)(ws);                 // 15,728,640 B
    u16* r1T   = (u16*)(ws + 15728640);      // 15,728,640 B
    u16* xupT  = (u16*)(ws + 31457280);      //  7,340,032 B
    u16* wT2   = (u16*)(ws + 38797312);      //  1,179,648 B
    u16* wc2T  = (u16*)(ws + 39976960);      //    589,824 B
    u16* wupT  = (u16*)(ws + 40566784);      //    131,072 B
    float* rng = (float*)(ws + 40697856);    //     32,768 B
    float* out = (float*)d_out;

    hipLaunchKernelGGL(k_prep, dim3(2192), dim3(256), 0, stream,
                       x, b1a, xT2, rng, w2, w1, wup, wT2, wc2T, wupT, (uint4*)r1T);
    hipLaunchKernelGGL(k_conv1x, dim3(1344), dim3(512), 0, stream,
                       xT2, wT2, b1b, b2a, r1T, x, rng, b1a, xupT);
    hipLaunchKernelGGL(k_conv2_mfma, dim3(NB * 7), dim3(512), 0, stream,
                       r1T, xupT, wc2T, wupT, scale, b2b, out);
}